// Round 2
// baseline (84.117 us; speedup 1.0000x reference)
//
#include <hip/hip_runtime.h>
#include <hip/hip_bf16.h>

#define NS 32
#define FD 512
#define K_INST 256
#define CHUNK 256            // floats per staged chunk (64 float4 per row)
#define GATE_BLOCKS 1024
#define TOTAL_BLOCKS (K_INST + GATE_BLOCKS)
#define GATE_N4 (65536*512/4)

__device__ __forceinline__ float wave_reduce_add(float v) {
  for (int off = 32; off; off >>= 1) v += __shfl_down(v, off, 64);
  return v;
}

__global__ __launch_bounds__(256) void fused_kernel(
    const float* __restrict__ dp, const float* __restrict__ gate,
    const int* __restrict__ inst_idx, const int* __restrict__ bg_idx,
    int* __restrict__ ctr,
    float* __restrict__ ws_gate, float* __restrict__ ws_hs,
    float* __restrict__ out) {

  // staging buffer (32 rows x 64 float4, XOR-swizzled); unioned with the
  // 4-wave partial-Gram buffer (4*1024 floats) -- disjoint lifetimes.
  __shared__ float4 sX4[NS * 64];          // 32768 B
  __shared__ float  sGD[NS * NS];          // 4096 B  (Gram, then dist, in place)
  __shared__ float  sMat[2][NS * NS];      // 8192 B
  __shared__ float  sRowM[2][NS];
  __shared__ float  sInv[NS];
  __shared__ int    sIdx[NS];
  __shared__ int    sHist[256];
  __shared__ int    sWaveSum[4];
  __shared__ float  sWaveRed[8];
  __shared__ unsigned sPrefix;
  __shared__ int    sWant;
  __shared__ int    sLast;

  float* sPartF = reinterpret_cast<float*>(sX4);   // [4][1024] alias

  const int tid  = threadIdx.x;
  const int bid  = blockIdx.x;
  const int lane = tid & 63;
  const int w    = tid >> 6;

  if (bid >= K_INST) {
    // ---- gate |x| partial sum ----
    const int gb = bid - K_INST;
    const float4* g4 = reinterpret_cast<const float4*>(gate);
    float s = 0.f;
    size_t base = (size_t)gb * 256 + tid;
    #pragma unroll 4
    for (int it = 0; it < 32; ++it) {
      float4 v = g4[base + (size_t)it * (GATE_BLOCKS * 256)];
      s += fabsf(v.x) + fabsf(v.y) + fabsf(v.z) + fabsf(v.w);
    }
    s = wave_reduce_add(s);
    if (lane == 0) sWaveRed[w] = s;
    __syncthreads();
    if (tid == 0) ws_gate[gb] = sWaveRed[0] + sWaveRed[1] + sWaveRed[2] + sWaveRed[3];
  } else {
    // ---- HSIC for instance k ----
    const int k  = bid;
    const int li = lane >> 3;   // 0..7
    const int lj = lane & 7;    // 0..7

    for (int m = 0; m < 2; ++m) {
      const int* idx = (m == 0 ? inst_idx : bg_idx) + k * NS;
      if (tid < NS) sIdx[tid] = idx[tid];
      __syncthreads();                                   // (a)

      float acc[4][4];
      #pragma unroll
      for (int a = 0; a < 4; ++a)
        #pragma unroll
        for (int b = 0; b < 4; ++b) acc[a][b] = 0.f;

      float4 pre[8];
      // prefetch chunk 0
      #pragma unroll
      for (int kk = 0; kk < 8; ++kk) {
        int r = w + 4 * kk;
        pre[kk] = *(reinterpret_cast<const float4*>(dp + (size_t)sIdx[r] * FD) + lane);
      }
      // store chunk 0 (swizzled)
      #pragma unroll
      for (int kk = 0; kk < 8; ++kk) {
        int r = w + 4 * kk;
        sX4[r * 64 + (lane ^ (r & 7))] = pre[kk];
      }
      __syncthreads();                                   // (b)
      // prefetch chunk 1 (loads in flight under chunk-0 compute)
      #pragma unroll
      for (int kk = 0; kk < 8; ++kk) {
        int r = w + 4 * kk;
        pre[kk] = *(reinterpret_cast<const float4*>(dp + (size_t)sIdx[r] * FD + CHUNK) + lane);
      }
      // Gram partial, chunk 0: wave w covers float4 cols [16w,16w+16)
      #pragma unroll 4
      for (int c = 16 * w; c < 16 * w + 16; ++c) {
        float4 xs[4], ys[4];
        #pragma unroll
        for (int s = 0; s < 4; ++s) {
          xs[s] = sX4[(li + 8 * s) * 64 + (c ^ li)];
          ys[s] = sX4[(lj + 8 * s) * 64 + (c ^ lj)];
        }
        #pragma unroll
        for (int a = 0; a < 4; ++a)
          #pragma unroll
          for (int b = 0; b < 4; ++b)
            acc[a][b] += xs[a].x * ys[b].x + xs[a].y * ys[b].y
                       + xs[a].z * ys[b].z + xs[a].w * ys[b].w;
      }
      __syncthreads();                                   // (c)
      #pragma unroll
      for (int kk = 0; kk < 8; ++kk) {
        int r = w + 4 * kk;
        sX4[r * 64 + (lane ^ (r & 7))] = pre[kk];
      }
      __syncthreads();                                   // (d)
      // Gram partial, chunk 1
      #pragma unroll 4
      for (int c = 16 * w; c < 16 * w + 16; ++c) {
        float4 xs[4], ys[4];
        #pragma unroll
        for (int s = 0; s < 4; ++s) {
          xs[s] = sX4[(li + 8 * s) * 64 + (c ^ li)];
          ys[s] = sX4[(lj + 8 * s) * 64 + (c ^ lj)];
        }
        #pragma unroll
        for (int a = 0; a < 4; ++a)
          #pragma unroll
          for (int b = 0; b < 4; ++b)
            acc[a][b] += xs[a].x * ys[b].x + xs[a].y * ys[b].y
                       + xs[a].z * ys[b].z + xs[a].w * ys[b].w;
      }
      __syncthreads();                                   // (e) all sX reads done
      // write per-wave partials into the (aliased) sPart buffer, bank-swizzled:
      // slot(A,B) = A*32 + (B ^ ((A&3)<<3))  -> 2 lanes/bank per store instr
      #pragma unroll
      for (int a = 0; a < 4; ++a)
        #pragma unroll
        for (int b = 0; b < 4; ++b) {
          int A = li + 8 * a, B = lj + 8 * b;
          sPartF[w * 1024 + A * 32 + (B ^ ((A & 3) << 3))] = acc[a][b];
        }
      __syncthreads();                                   // (f)
      // cross-wave reduce -> true-index Gram in sGD
      for (int p = tid; p < 1024; p += 256) {
        float s = sPartF[p] + sPartF[1024 + p] + sPartF[2048 + p] + sPartF[3072 + p];
        int A = p >> 5, Bx = p & 31;
        sGD[A * 32 + (Bx ^ ((A & 3) << 3))] = s;
      }
      __syncthreads();                                   // (g)
      if (tid < NS) sInv[tid] = 1.f / fmaxf(sqrtf(sGD[tid * 33]), 1e-12f);
      __syncthreads();                                   // (h)
      for (int p = tid; p < 1024; p += 256) {
        int i = p >> 5, j = p & 31;
        sGD[p] = (i == j) ? 0.f
                          : fmaxf(2.f - 2.f * sGD[p] * sInv[i] * sInv[j], 0.f);
      }
      if (tid == 0) { sPrefix = 0u; sWant = (NS * NS - 1) / 2; }
      __syncthreads();                                   // (i)

      // exact lower-median via 4-pass MSD radix select on f32 bit patterns
      for (int shift = 24; shift >= 0; shift -= 8) {
        sHist[tid] = 0;
        __syncthreads();
        unsigned pref = sPrefix;
        int want = sWant;
        unsigned hi_mask = (shift == 24) ? 0u : (0xFFFFFFFFu << (shift + 8));
        for (int q = tid; q < NS * NS; q += 256) {
          unsigned u = __float_as_uint(sGD[q]);
          if ((u & hi_mask) == pref) atomicAdd(&sHist[(u >> shift) & 255], 1);
        }
        __syncthreads();
        int v = sHist[tid];
        int x = v;
        for (int off = 1; off < 64; off <<= 1) {
          int y = __shfl_up(x, off, 64);
          if (lane >= off) x += y;
        }
        if (lane == 63) sWaveSum[w] = x;
        __syncthreads();
        int add = 0;
        for (int ww = 0; ww < w; ++ww) add += sWaveSum[ww];
        x += add;
        int ex = x - v;
        if (ex <= want && want < ex + v) {
          sPrefix = pref | ((unsigned)tid << shift);
          sWant   = want - ex;
        }
        __syncthreads();
      }
      float sigma2 = __uint_as_float(sPrefix) + 1e-5f;

      for (int q = tid; q < NS * NS; q += 256)
        sMat[m][q] = expf(-sGD[q] / (2.f * sigma2));
      __syncthreads();                                   // (j)
      {
        int r = tid >> 3, g = tid & 7;
        float p = 0.f;
        for (int s = 0; s < 4; ++s) p += sMat[m][r * 32 + g + 8 * s];
        for (int off = 4; off; off >>= 1) p += __shfl_down(p, off, 8);
        if (g == 0) sRowM[m][r] = p * (1.f / 32.f);
      }
      __syncthreads();                                   // (k)
    }

    // hsic = sum_ij (K_ij - rK_i)(L_ij - rL_j) / 961  (L symmetric)
    float part = 0.f;
    for (int q = tid; q < NS * NS; q += 256) {
      int i = q >> 5, j = q & 31;
      part += (sMat[0][q] - sRowM[0][i]) * (sMat[1][q] - sRowM[1][j]);
    }
    part = wave_reduce_add(part);
    if (lane == 0) sWaveRed[w] = part;
    __syncthreads();
    if (tid == 0)
      ws_hs[k] = (sWaveRed[0] + sWaveRed[1] + sWaveRed[2] + sWaveRed[3]) * (1.f / 961.f);
  }

  // ---- last-block finalize ----
  if (tid == 0) {
    __threadfence();
    sLast = (atomicAdd(ctr, 1) == TOTAL_BLOCKS - 1) ? 1 : 0;
  }
  __syncthreads();
  if (sLast) {
    __threadfence();
    float g = 0.f;
    for (int i = tid; i < GATE_BLOCKS; i += 256) g += ws_gate[i];
    g = wave_reduce_add(g);
    if (lane == 0) sWaveRed[w] = g;
    float h = (tid < K_INST) ? ws_hs[tid] : 0.f;
    h = wave_reduce_add(h);
    if (lane == 0) sWaveRed[4 + w] = h;
    __syncthreads();
    if (tid == 0) {
      float gsum = sWaveRed[0] + sWaveRed[1] + sWaveRed[2] + sWaveRed[3];
      float hsum = sWaveRed[4] + sWaveRed[5] + sWaveRed[6] + sWaveRed[7];
      out[0] = hsum * (1.f / 256.f) + 1e-3f * (gsum / (65536.f * 512.f));
    }
  }
}

extern "C" void kernel_launch(void* const* d_in, const int* in_sizes, int n_in,
                              void* d_out, int out_size, void* d_ws, size_t ws_size,
                              hipStream_t stream) {
  const float* dp   = (const float*)d_in[0];
  const float* gate = (const float*)d_in[1];
  const int*   inst = (const int*)d_in[2];
  const int*   bg   = (const int*)d_in[3];
  float* out = (float*)d_out;
  float* ws  = (float*)d_ws;
  int*   ctr = (int*)d_ws;             // [0]
  float* ws_gate = ws + 16;            // [GATE_BLOCKS]
  float* ws_hs   = ws + 16 + GATE_BLOCKS; // [K_INST]

  hipMemsetAsync(d_ws, 0, 4, stream);
  fused_kernel<<<TOTAL_BLOCKS, 256, 0, stream>>>(dp, gate, inst, bg, ctr, ws_gate, ws_hs, out);
}

// Round 3
// 52.409 us; speedup vs baseline: 1.6050x; 1.6050x over previous
//
#include <hip/hip_runtime.h>
#include <hip/hip_bf16.h>

#define NS 32
#define FD 512
#define K_INST 256
#define CHUNK 256            // floats per staged chunk (64 float4 per row)
#define GATE_BLOCKS 1024
#define GATE_N4 (65536*512/4)

__device__ __forceinline__ float wave_reduce_add(float v) {
  for (int off = 32; off; off >>= 1) v += __shfl_down(v, off, 64);
  return v;
}

__global__ __launch_bounds__(256) void fused_kernel(
    const float* __restrict__ dp, const float* __restrict__ gate,
    const int* __restrict__ inst_idx, const int* __restrict__ bg_idx,
    float* __restrict__ ws_gate, float* __restrict__ ws_hs) {

  // staging buffer (32 rows x 64 float4, XOR-swizzled); unioned with the
  // 4-wave partial-Gram buffer (4*1024 floats) -- disjoint lifetimes.
  __shared__ float4 sX4[NS * 64];          // 32768 B
  __shared__ float  sGD[NS * NS];          // 4096 B  (Gram, then dist, in place)
  __shared__ float  sMat[2][NS * NS];      // 8192 B
  __shared__ float  sRowM[2][NS];
  __shared__ float  sInv[NS];
  __shared__ int    sIdx[NS];
  __shared__ int    sHist[256];
  __shared__ int    sWaveSum[4];
  __shared__ float  sWaveRed[8];
  __shared__ unsigned sPrefix;
  __shared__ int    sWant;

  float* sPartF = reinterpret_cast<float*>(sX4);   // [4][1024] alias

  const int tid  = threadIdx.x;
  const int bid  = blockIdx.x;
  const int lane = tid & 63;
  const int w    = tid >> 6;

  if (bid >= K_INST) {
    // ---- gate |x| partial sum ----
    const int gb = bid - K_INST;
    const float4* g4 = reinterpret_cast<const float4*>(gate);
    float s = 0.f;
    size_t base = (size_t)gb * 256 + tid;
    #pragma unroll 4
    for (int it = 0; it < 32; ++it) {
      float4 v = g4[base + (size_t)it * (GATE_BLOCKS * 256)];
      s += fabsf(v.x) + fabsf(v.y) + fabsf(v.z) + fabsf(v.w);
    }
    s = wave_reduce_add(s);
    if (lane == 0) sWaveRed[w] = s;
    __syncthreads();
    if (tid == 0) ws_gate[gb] = sWaveRed[0] + sWaveRed[1] + sWaveRed[2] + sWaveRed[3];
    return;
  }

  // ---- HSIC for instance k ----
  const int k  = bid;
  const int li = lane >> 3;   // 0..7
  const int lj = lane & 7;    // 0..7

  for (int m = 0; m < 2; ++m) {
    const int* idx = (m == 0 ? inst_idx : bg_idx) + k * NS;
    if (tid < NS) sIdx[tid] = idx[tid];
    __syncthreads();                                   // (a)

    float acc[4][4];
    #pragma unroll
    for (int a = 0; a < 4; ++a)
      #pragma unroll
      for (int b = 0; b < 4; ++b) acc[a][b] = 0.f;

    float4 pre[8];
    // prefetch chunk 0
    #pragma unroll
    for (int kk = 0; kk < 8; ++kk) {
      int r = w + 4 * kk;
      pre[kk] = *(reinterpret_cast<const float4*>(dp + (size_t)sIdx[r] * FD) + lane);
    }
    // store chunk 0 (swizzled)
    #pragma unroll
    for (int kk = 0; kk < 8; ++kk) {
      int r = w + 4 * kk;
      sX4[r * 64 + (lane ^ (r & 7))] = pre[kk];
    }
    __syncthreads();                                   // (b)
    // prefetch chunk 1 (loads in flight under chunk-0 compute)
    #pragma unroll
    for (int kk = 0; kk < 8; ++kk) {
      int r = w + 4 * kk;
      pre[kk] = *(reinterpret_cast<const float4*>(dp + (size_t)sIdx[r] * FD + CHUNK) + lane);
    }
    // Gram partial, chunk 0: wave w covers float4 cols [16w,16w+16)
    #pragma unroll 4
    for (int c = 16 * w; c < 16 * w + 16; ++c) {
      float4 xs[4], ys[4];
      #pragma unroll
      for (int s = 0; s < 4; ++s) {
        xs[s] = sX4[(li + 8 * s) * 64 + (c ^ li)];
        ys[s] = sX4[(lj + 8 * s) * 64 + (c ^ lj)];
      }
      #pragma unroll
      for (int a = 0; a < 4; ++a)
        #pragma unroll
        for (int b = 0; b < 4; ++b)
          acc[a][b] += xs[a].x * ys[b].x + xs[a].y * ys[b].y
                     + xs[a].z * ys[b].z + xs[a].w * ys[b].w;
    }
    __syncthreads();                                   // (c)
    #pragma unroll
    for (int kk = 0; kk < 8; ++kk) {
      int r = w + 4 * kk;
      sX4[r * 64 + (lane ^ (r & 7))] = pre[kk];
    }
    __syncthreads();                                   // (d)
    // Gram partial, chunk 1
    #pragma unroll 4
    for (int c = 16 * w; c < 16 * w + 16; ++c) {
      float4 xs[4], ys[4];
      #pragma unroll
      for (int s = 0; s < 4; ++s) {
        xs[s] = sX4[(li + 8 * s) * 64 + (c ^ li)];
        ys[s] = sX4[(lj + 8 * s) * 64 + (c ^ lj)];
      }
      #pragma unroll
      for (int a = 0; a < 4; ++a)
        #pragma unroll
        for (int b = 0; b < 4; ++b)
          acc[a][b] += xs[a].x * ys[b].x + xs[a].y * ys[b].y
                     + xs[a].z * ys[b].z + xs[a].w * ys[b].w;
    }
    __syncthreads();                                   // (e) all sX reads done
    // write per-wave partials into the (aliased) sPart buffer, bank-swizzled:
    // slot(A,B) = A*32 + (B ^ ((A&3)<<3))  -> 2 lanes/bank per store instr
    #pragma unroll
    for (int a = 0; a < 4; ++a)
      #pragma unroll
      for (int b = 0; b < 4; ++b) {
        int A = li + 8 * a, B = lj + 8 * b;
        sPartF[w * 1024 + A * 32 + (B ^ ((A & 3) << 3))] = acc[a][b];
      }
    __syncthreads();                                   // (f)
    // cross-wave reduce -> true-index Gram in sGD
    for (int p = tid; p < 1024; p += 256) {
      float s = sPartF[p] + sPartF[1024 + p] + sPartF[2048 + p] + sPartF[3072 + p];
      int A = p >> 5, Bx = p & 31;
      sGD[A * 32 + (Bx ^ ((A & 3) << 3))] = s;
    }
    __syncthreads();                                   // (g)
    if (tid < NS) sInv[tid] = 1.f / fmaxf(sqrtf(sGD[tid * 33]), 1e-12f);
    __syncthreads();                                   // (h)
    for (int p = tid; p < 1024; p += 256) {
      int i = p >> 5, j = p & 31;
      sGD[p] = (i == j) ? 0.f
                        : fmaxf(2.f - 2.f * sGD[p] * sInv[i] * sInv[j], 0.f);
    }
    if (tid == 0) { sPrefix = 0u; sWant = (NS * NS - 1) / 2; }
    __syncthreads();                                   // (i)

    // exact lower-median via 4-pass MSD radix select on f32 bit patterns
    for (int shift = 24; shift >= 0; shift -= 8) {
      sHist[tid] = 0;
      __syncthreads();
      unsigned pref = sPrefix;
      int want = sWant;
      unsigned hi_mask = (shift == 24) ? 0u : (0xFFFFFFFFu << (shift + 8));
      for (int q = tid; q < NS * NS; q += 256) {
        unsigned u = __float_as_uint(sGD[q]);
        if ((u & hi_mask) == pref) atomicAdd(&sHist[(u >> shift) & 255], 1);
      }
      __syncthreads();
      int v = sHist[tid];
      int x = v;
      for (int off = 1; off < 64; off <<= 1) {
        int y = __shfl_up(x, off, 64);
        if (lane >= off) x += y;
      }
      if (lane == 63) sWaveSum[w] = x;
      __syncthreads();
      int add = 0;
      for (int ww = 0; ww < w; ++ww) add += sWaveSum[ww];
      x += add;
      int ex = x - v;
      if (ex <= want && want < ex + v) {
        sPrefix = pref | ((unsigned)tid << shift);
        sWant   = want - ex;
      }
      __syncthreads();
    }
    float sigma2 = __uint_as_float(sPrefix) + 1e-5f;

    for (int q = tid; q < NS * NS; q += 256)
      sMat[m][q] = expf(-sGD[q] / (2.f * sigma2));
    __syncthreads();                                   // (j)
    {
      int r = tid >> 3, g = tid & 7;
      float p = 0.f;
      for (int s = 0; s < 4; ++s) p += sMat[m][r * 32 + g + 8 * s];
      for (int off = 4; off; off >>= 1) p += __shfl_down(p, off, 8);
      if (g == 0) sRowM[m][r] = p * (1.f / 32.f);
    }
    __syncthreads();                                   // (k)
  }

  // hsic = sum_ij (K_ij - rK_i)(L_ij - rL_j) / 961  (L symmetric)
  float part = 0.f;
  for (int q = tid; q < NS * NS; q += 256) {
    int i = q >> 5, j = q & 31;
    part += (sMat[0][q] - sRowM[0][i]) * (sMat[1][q] - sRowM[1][j]);
  }
  part = wave_reduce_add(part);
  if (lane == 0) sWaveRed[w] = part;
  __syncthreads();
  if (tid == 0)
    ws_hs[k] = (sWaveRed[0] + sWaveRed[1] + sWaveRed[2] + sWaveRed[3]) * (1.f / 961.f);
}

__global__ __launch_bounds__(256) void final_kernel(
    const float* __restrict__ ws_gate, const float* __restrict__ ws_hs,
    float* __restrict__ out) {
  __shared__ float sW[8];
  const int tid = threadIdx.x, lane = tid & 63, wave = tid >> 6;
  float g = 0.f;
  for (int i = tid; i < GATE_BLOCKS; i += 256) g += ws_gate[i];
  g = wave_reduce_add(g);
  if (lane == 0) sW[wave] = g;
  float h = (tid < K_INST) ? ws_hs[tid] : 0.f;
  h = wave_reduce_add(h);
  if (lane == 0) sW[4 + wave] = h;
  __syncthreads();
  if (tid == 0) {
    float gsum = sW[0] + sW[1] + sW[2] + sW[3];
    float hsum = sW[4] + sW[5] + sW[6] + sW[7];
    out[0] = hsum * (1.f / 256.f) + 1e-3f * (gsum / (65536.f * 512.f));
  }
}

extern "C" void kernel_launch(void* const* d_in, const int* in_sizes, int n_in,
                              void* d_out, int out_size, void* d_ws, size_t ws_size,
                              hipStream_t stream) {
  const float* dp   = (const float*)d_in[0];
  const float* gate = (const float*)d_in[1];
  const int*   inst = (const int*)d_in[2];
  const int*   bg   = (const int*)d_in[3];
  float* out = (float*)d_out;
  float* ws  = (float*)d_ws;
  float* ws_gate = ws;                 // [GATE_BLOCKS]
  float* ws_hs   = ws + GATE_BLOCKS;   // [K_INST]

  fused_kernel<<<K_INST + GATE_BLOCKS, 256, 0, stream>>>(dp, gate, inst, bg, ws_gate, ws_hs);
  final_kernel<<<1, 256, 0, stream>>>(ws_gate, ws_hs, out);
}

// Round 4
// 38.009 us; speedup vs baseline: 2.2131x; 1.3789x over previous
//
#include <hip/hip_runtime.h>
#include <hip/hip_bf16.h>

#define NS 32
#define FD 512
#define K_INST 256
#define CHUNK 256            // floats of FD staged per pass
#define C4 (CHUNK/4)         // 64 float4 per row-chunk
#define PADF 260             // staged row stride in floats
#define PAD4 (PADF/4)        // 65
#define MPAD 33              // 32x32 matrix padded to 33 cols
#define HSIC_BLOCKS 512      // (k, m) pairs: k = bid>>1, m = bid&1
#define GATE_BLOCKS 1024
#define GATE_N4 (65536*512/4)

__device__ __forceinline__ float wave_reduce_add(float v) {
  for (int off = 32; off; off >>= 1) v += __shfl_down(v, off, 64);
  return v;
}

__global__ __launch_bounds__(256) void fused_kernel(
    const float* __restrict__ dp, const float* __restrict__ gate,
    const int* __restrict__ inst_idx, const int* __restrict__ bg_idx,
    float* __restrict__ ws_gate, float* __restrict__ ws_mats,
    float* __restrict__ ws_means) {

  __shared__ float sX[NS * PADF];        // 33280 B staging
  __shared__ float sD[NS * MPAD];        // 4224 B (dist, then exp in place)
  __shared__ float sRowM[NS];
  __shared__ float sInv[NS];
  __shared__ float sN2[NS];
  __shared__ int   sIdx[NS];
  __shared__ int   sHist[256];
  __shared__ int   sWaveSum[4];
  __shared__ float sWaveRed[4];
  __shared__ unsigned sPrefix;
  __shared__ int   sWant;

  const int tid  = threadIdx.x;
  const int bid  = blockIdx.x;
  const int lane = tid & 63;
  const int w    = tid >> 6;

  if (bid >= HSIC_BLOCKS) {
    // ---- gate |x| partial sum (grid-stride, float4) ----
    const int gb = bid - HSIC_BLOCKS;
    const float4* g4 = reinterpret_cast<const float4*>(gate);
    float s = 0.f;
    for (size_t i = (size_t)gb * 256 + tid; i < (size_t)GATE_N4; i += (size_t)GATE_BLOCKS * 256) {
      float4 v = g4[i];
      s += fabsf(v.x) + fabsf(v.y) + fabsf(v.z) + fabsf(v.w);
    }
    s = wave_reduce_add(s);
    if (lane == 0) sWaveRed[w] = s;
    __syncthreads();
    if (tid == 0) ws_gate[gb] = sWaveRed[0] + sWaveRed[1] + sWaveRed[2] + sWaveRed[3];
    return;
  }

  // ---- one RBF matrix: instance k, side m ----
  const int k = bid >> 1;
  const int m = bid & 1;
  const int ti = tid >> 4;   // 0..15
  const int tj = tid & 15;   // 0..15
  const float4* sX4 = reinterpret_cast<const float4*>(sX);

  const int* idx = (m == 0 ? inst_idx : bg_idx) + k * NS;
  if (tid < NS) sIdx[tid] = idx[tid];
  __syncthreads();

  // raw Gram, strided 2x2 tile per thread: rows {ti,ti+16} x cols {tj,tj+16}
  float a00 = 0.f, a01 = 0.f, a10 = 0.f, a11 = 0.f;
  for (int ch = 0; ch < 2; ++ch) {
    for (int q = tid; q < NS * C4; q += 256) {
      int r = q >> 6, c = q & 63;
      float4 v = *(reinterpret_cast<const float4*>(dp + (size_t)sIdx[r] * FD + ch * CHUNK) + c);
      *(reinterpret_cast<float4*>(&sX[r * PADF]) + c) = v;
    }
    __syncthreads();
    #pragma unroll 4
    for (int c = 0; c < C4; ++c) {
      float4 x0 = sX4[ti * PAD4 + c];
      float4 x1 = sX4[(ti + 16) * PAD4 + c];
      float4 y0 = sX4[tj * PAD4 + c];
      float4 y1 = sX4[(tj + 16) * PAD4 + c];
      a00 += x0.x*y0.x + x0.y*y0.y + x0.z*y0.z + x0.w*y0.w;
      a01 += x0.x*y1.x + x0.y*y1.y + x0.z*y1.z + x0.w*y1.w;
      a10 += x1.x*y0.x + x1.y*y0.y + x1.z*y0.z + x1.w*y0.w;
      a11 += x1.x*y1.x + x1.y*y1.y + x1.z*y1.z + x1.w*y1.w;
    }
    __syncthreads();
  }

  // norms from Gram diagonal
  if (ti == tj) { sN2[ti] = a00; sN2[ti + 16] = a11; }
  __syncthreads();
  if (tid < NS) sInv[tid] = 1.f / fmaxf(sqrtf(sN2[tid]), 1e-12f);
  __syncthreads();

  // dist = max(2 - 2*Gn, 0), exact 0 diagonal
  {
    float i0 = sInv[ti], i1 = sInv[ti + 16], j0 = sInv[tj], j1 = sInv[tj + 16];
    sD[ti * MPAD + tj]               = (ti == tj) ? 0.f : fmaxf(2.f - 2.f * a00 * i0 * j0, 0.f);
    sD[ti * MPAD + (tj + 16)]        = fmaxf(2.f - 2.f * a01 * i0 * j1, 0.f);
    sD[(ti + 16) * MPAD + tj]        = fmaxf(2.f - 2.f * a10 * i1 * j0, 0.f);
    sD[(ti + 16) * MPAD + (tj + 16)] = (ti == tj) ? 0.f : fmaxf(2.f - 2.f * a11 * i1 * j1, 0.f);
  }
  if (tid == 0) { sPrefix = 0u; sWant = (NS * NS - 1) / 2; }  // 511th smallest
  __syncthreads();

  // exact lower-median via 4-pass MSD radix select on f32 bit patterns (all >= 0)
  for (int shift = 24; shift >= 0; shift -= 8) {
    sHist[tid] = 0;
    __syncthreads();
    unsigned pref = sPrefix;
    int want = sWant;
    unsigned hi_mask = (shift == 24) ? 0u : (0xFFFFFFFFu << (shift + 8));
    for (int q = tid; q < NS * NS; q += 256) {
      unsigned u = __float_as_uint(sD[(q >> 5) * MPAD + (q & 31)]);
      if ((u & hi_mask) == pref) atomicAdd(&sHist[(u >> shift) & 255], 1);
    }
    __syncthreads();
    int v = sHist[tid];
    int x = v;
    for (int off = 1; off < 64; off <<= 1) {
      int y = __shfl_up(x, off, 64);
      if (lane >= off) x += y;
    }
    if (lane == 63) sWaveSum[w] = x;
    __syncthreads();
    int add = 0;
    for (int ww = 0; ww < w; ++ww) add += sWaveSum[ww];
    x += add;
    int ex = x - v;            // exclusive prefix over 256 bins
    if (ex <= want && want < ex + v) {
      sPrefix = pref | ((unsigned)tid << shift);
      sWant   = want - ex;
    }
    __syncthreads();
  }
  float sigma2 = __uint_as_float(sPrefix) + 1e-5f;

  // exp in place
  for (int q = tid; q < NS * NS; q += 256) {
    int i = q >> 5, j = q & 31;
    sD[i * MPAD + j] = expf(-sD[i * MPAD + j] / (2.f * sigma2));
  }
  __syncthreads();

  // row means
  {
    int r = tid >> 3, g = tid & 7;
    float p = 0.f;
    for (int s = 0; s < 4; ++s) p += sD[r * MPAD + g + 8 * s];
    for (int off = 4; off; off >>= 1) p += __shfl_down(p, off, 8);
    if (g == 0) sRowM[r] = p * (1.f / 32.f);
  }
  __syncthreads();

  // write matrix (compact [1024]) + row means to workspace
  float* mat = ws_mats + (size_t)bid * 1024;
  for (int q = tid; q < NS * NS; q += 256)
    mat[q] = sD[(q >> 5) * MPAD + (q & 31)];
  if (tid < NS) ws_means[bid * NS + tid] = sRowM[tid];
}

__global__ __launch_bounds__(256) void contract_kernel(
    const float* __restrict__ ws_mats, const float* __restrict__ ws_means,
    float* __restrict__ ws_hs) {
  __shared__ float sRM[2][NS];
  __shared__ float sWaveRed[4];
  const int k = blockIdx.x;
  const int tid = threadIdx.x, lane = tid & 63, w = tid >> 6;
  const float* Km = ws_mats + (size_t)(k * 2 + 0) * 1024;
  const float* Lm = ws_mats + (size_t)(k * 2 + 1) * 1024;
  if (tid < 64) sRM[tid >> 5][tid & 31] = ws_means[(k * 2 + (tid >> 5)) * NS + (tid & 31)];
  __syncthreads();
  float part = 0.f;
  for (int q = tid; q < NS * NS; q += 256) {
    int i = q >> 5, j = q & 31;
    part += (Km[q] - sRM[0][i]) * (Lm[q] - sRM[1][j]);  // L symmetric: L_ji == L_ij
  }
  part = wave_reduce_add(part);
  if (lane == 0) sWaveRed[w] = part;
  __syncthreads();
  if (tid == 0)
    ws_hs[k] = (sWaveRed[0] + sWaveRed[1] + sWaveRed[2] + sWaveRed[3]) * (1.f / 961.f);
}

__global__ __launch_bounds__(256) void final_kernel(
    const float* __restrict__ ws_gate, const float* __restrict__ ws_hs,
    float* __restrict__ out) {
  __shared__ float sW[8];
  const int tid = threadIdx.x, lane = tid & 63, wave = tid >> 6;
  float g = 0.f;
  for (int i = tid; i < GATE_BLOCKS; i += 256) g += ws_gate[i];
  g = wave_reduce_add(g);
  if (lane == 0) sW[wave] = g;
  float h = (tid < K_INST) ? ws_hs[tid] : 0.f;
  h = wave_reduce_add(h);
  if (lane == 0) sW[4 + wave] = h;
  __syncthreads();
  if (tid == 0) {
    float gsum = sW[0] + sW[1] + sW[2] + sW[3];
    float hsum = sW[4] + sW[5] + sW[6] + sW[7];
    out[0] = hsum * (1.f / 256.f) + 1e-3f * (gsum / (65536.f * 512.f));
  }
}

extern "C" void kernel_launch(void* const* d_in, const int* in_sizes, int n_in,
                              void* d_out, int out_size, void* d_ws, size_t ws_size,
                              hipStream_t stream) {
  const float* dp   = (const float*)d_in[0];
  const float* gate = (const float*)d_in[1];
  const int*   inst = (const int*)d_in[2];
  const int*   bg   = (const int*)d_in[3];
  float* out = (float*)d_out;
  float* ws  = (float*)d_ws;
  float* ws_gate  = ws;                          // [1024]
  float* ws_hs    = ws + 1024;                   // [256]
  float* ws_means = ws + 1024 + 256;             // [512*32]
  float* ws_mats  = ws + 1024 + 256 + 512 * 32;  // [512*1024]

  fused_kernel<<<HSIC_BLOCKS + GATE_BLOCKS, 256, 0, stream>>>(
      dp, gate, inst, bg, ws_gate, ws_mats, ws_means);
  contract_kernel<<<K_INST, 256, 0, stream>>>(ws_mats, ws_means, ws_hs);
  final_kernel<<<1, 256, 0, stream>>>(ws_gate, ws_hs, out);
}